// Round 2
// baseline (1759.960 us; speedup 1.0000x reference)
//
#include <hip/hip_runtime.h>
#include <math.h>

// ---------------------------------------------------------------------------
// Aux-free MoE, capacity-routed top-2, E=16 experts.
// B=16384, F=1024, H=4096, O=1024, cap=2560 (multiple of 256 -> capR==cap).
// Heavy GEMMs: 256x256 tile, BK=32, 3-buffer LDS pipeline (stage t+2 while
// computing t; publish t+1 with counted vmcnt(4) - never vmcnt(0) in loop),
// XOR-swizzled LDS chunks, setprio MFMA clusters, bijective XCD block swizzle.
// Gating in fp64 to match the reference's expert selection exactly.
// ---------------------------------------------------------------------------

typedef __attribute__((ext_vector_type(8))) short bf16x8;
typedef __attribute__((ext_vector_type(4))) float floatx4;

static __device__ __forceinline__ unsigned short f2bf(float f) {
  union { float f; unsigned u; } v; v.f = f;
  unsigned u = v.u;
  return (unsigned short)((u + 0x7fffu + ((u >> 16) & 1u)) >> 16);  // RNE
}

static __device__ __forceinline__ void gload_lds16(const void* g, void* l) {
  __builtin_amdgcn_global_load_lds(
      (const __attribute__((address_space(1))) unsigned int*)g,
      (__attribute__((address_space(3))) unsigned int*)l, 16, 0, 0);
}

// --------------------------- fp32 -> bf16 convert ---------------------------
__global__ void k_cvt_bf16(const float* __restrict__ src,
                           unsigned short* __restrict__ dst, long n4) {
  long i = (long)blockIdx.x * blockDim.x + threadIdx.x;
  if (i >= n4) return;
  float4 f = ((const float4*)src)[i];
  ushort4 o;
  o.x = f2bf(f.x); o.y = f2bf(f.y); o.z = f2bf(f.z); o.w = f2bf(f.w);
  ((ushort4*)dst)[i] = o;
}

// ----------------- transpose + convert: (E,K,N) f32 -> (E,N,K) bf16 --------
__global__ void k_txp_bf16(const float* __restrict__ src,
                           unsigned short* __restrict__ dst, int Kd, int Nd) {
  __shared__ float tile[32][33];
  int e = blockIdx.z;
  int n0 = blockIdx.x * 32;
  int k0 = blockIdx.y * 32;
  int tx = threadIdx.x;  // 0..31
  int ty = threadIdx.y;  // 0..7
  const float* s = src + (size_t)e * Kd * Nd;
#pragma unroll
  for (int j = 0; j < 4; ++j) {
    int k = ty + j * 8;
    tile[k][tx] = s[(size_t)(k0 + k) * Nd + n0 + tx];
  }
  __syncthreads();
  unsigned short* d = dst + (size_t)e * Kd * Nd;
#pragma unroll
  for (int j = 0; j < 4; ++j) {
    int n = ty + j * 8;
    d[(size_t)(n0 + n) * Kd + k0 + tx] = f2bf(tile[tx][n]);
  }
}

// ------------------------------- gating (fp64) ------------------------------
__global__ __launch_bounds__(256) void k_gating(
    const float* __restrict__ feat, const float* __restrict__ Wg,
    const float* __restrict__ bg, const float* __restrict__ ebias,
    int* __restrict__ topki, float* __restrict__ topkw,
    int* __restrict__ hist, int B, int F) {
  __shared__ float WgS[16 * 1024];  // 64 KB
  for (int i = threadIdx.x; i < 16 * F; i += blockDim.x) WgS[i] = Wg[i];
  __syncthreads();
  int lane = threadIdx.x & 63;
  int wid = threadIdx.x >> 6;
  int gw = blockIdx.x * 4 + wid;
  int nw = gridDim.x * 4;
  int per = B / nw;
  for (int it = 0; it < per; ++it) {
    int t = gw * per + it;
    double acc[16];
#pragma unroll
    for (int e = 0; e < 16; ++e) acc[e] = 0.0;
    const float* fr = feat + (size_t)t * F;
    for (int c = 0; c < F / 64; ++c) {
      double fd = (double)fr[c * 64 + lane];
#pragma unroll
      for (int e = 0; e < 16; ++e)
        acc[e] += fd * (double)WgS[e * F + c * 64 + lane];
    }
#pragma unroll
    for (int e = 0; e < 16; ++e) {
#pragma unroll
      for (int off = 32; off >= 1; off >>= 1)
        acc[e] += __shfl_xor(acc[e], off);
    }
    double s[16];
#pragma unroll
    for (int e = 0; e < 16; ++e)
      s[e] = acc[e] + (double)bg[e] + (double)ebias[e];
    int e1 = 0; double s1 = s[0];
#pragma unroll
    for (int e = 1; e < 16; ++e) if (s[e] > s1) { s1 = s[e]; e1 = e; }
    int e2 = -1; double s2 = -1e300;
#pragma unroll
    for (int e = 0; e < 16; ++e)
      if (e != e1 && s[e] > s2) { s2 = s[e]; e2 = e; }
    double d = exp(s2 - s1);
    float w1 = (float)(1.0 / (1.0 + d));
    float w2 = (float)(d / (1.0 + d));
    if (lane == 0) {
      topki[t * 2 + 0] = e1; topki[t * 2 + 1] = e2;
      topkw[t * 2 + 0] = w1; topkw[t * 2 + 1] = w2;
      atomicAdd(&hist[(t >> 8) * 16 + e1], 1);
      atomicAdd(&hist[(t >> 8) * 16 + e2], 1);
    }
  }
}

// ------------------------- chunk-offset scan (1 block) ----------------------
__global__ void k_scan(const int* __restrict__ hist, int* __restrict__ choff,
                       int* __restrict__ cntcl, int nchunk, int cap) {
  int e = threadIdx.x;
  if (e < 16) {
    int off = 0;
    for (int c = 0; c < nchunk; ++c) {
      choff[c * 16 + e] = off;
      off += hist[c * 16 + e];
    }
    cntcl[e] = off < cap ? off : cap;
  }
}

// -------------------- build per-expert slot lists (ordered) -----------------
__global__ __launch_bounds__(64) void k_build(
    const int* __restrict__ topki, const float* __restrict__ topkw,
    const int* __restrict__ choff, int* __restrict__ list,
    float* __restrict__ wlist, int cap, int capR) {
  int c = blockIdx.x;
  int lane = threadIdx.x;
  int run[16];
#pragma unroll
  for (int e = 0; e < 16; ++e) run[e] = choff[c * 16 + e];
  unsigned long long below = (lane == 63) ? 0x7fffffffffffffffull
                                          : ((1ull << lane) - 1ull);
  for (int r = 0; r < 4; ++r) {
    int t = c * 256 + r * 64 + lane;
    int e1 = topki[t * 2 + 0], e2 = topki[t * 2 + 1];
    float w1 = topkw[t * 2 + 0], w2 = topkw[t * 2 + 1];
    int p1 = -1, p2 = -1;
#pragma unroll
    for (int e = 0; e < 16; ++e) {
      unsigned long long m = __ballot(e1 == e) | __ballot(e2 == e);
      int rk = run[e] + __popcll(m & below);
      if (e1 == e) p1 = rk;
      if (e2 == e) p2 = rk;
      run[e] += __popcll(m);
    }
    if (p1 >= 0 && p1 < cap) { list[e1 * capR + p1] = t; wlist[e1 * capR + p1] = w1; }
    if (p2 >= 0 && p2 < cap) { list[e2 * capR + p2] = t; wlist[e2 * capR + p2] = w2; }
  }
}

// ----------------------- pad unused slots (token 0, w 0) --------------------
__global__ void k_padfill(const int* __restrict__ cntcl, int* __restrict__ list,
                          float* __restrict__ wlist, int capR) {
  int e = blockIdx.x;
  int cnt = cntcl[e];
  for (int s = cnt + (int)threadIdx.x; s < capR; s += (int)blockDim.x) {
    list[e * capR + s] = 0;
    wlist[e * capR + s] = 0.0f;
  }
}

// ------------------------------ bf16 MFMA GEMM ------------------------------
// 256x256 tile, BK=32, 8 waves (2Mx4N, 128x64 out each).
// LDS: 3 buffers x 32KB (A 16KB: 256 rows x 64B; B 16KB). Row = 4 x 16B
// chunks, stored at slot = chunk ^ ((row>>1)&3) via pre-swizzled global src
// (linear global_load_lds dest); reads apply the same XOR -> 2-way (free).
// Pipeline: while computing tile t (buf t%3), stage tile t+2 (buf (t+2)%3);
// publish t+1 at tile end with vmcnt(4) (t+2's 4 loads stay in flight).
// Per tile: 2 phases x {ds_reads, barrier, setprio(1), 16 MFMA, setprio(0),
// barrier}; staging issued in phase 1 (distance to wait = 3 phases).
// MODE 0: A rows gathered from featbf via list; epilogue relu(acc+b1) -> Hout
// MODE 1: A rows from Hbuf; epilogue w*(acc+b2) atomic-scatter -> out[token]
#define VM_WAIT4 asm volatile("s_waitcnt vmcnt(4)" ::: "memory")
#define VM_WAIT0 asm volatile("s_waitcnt vmcnt(0)" ::: "memory")

template <int MODE>
__global__ __launch_bounds__(512, 2) void k_gemm(
    const unsigned short* __restrict__ A, const unsigned short* __restrict__ Bt,
    const float* __restrict__ bias, const int* __restrict__ list,
    const float* __restrict__ wlist, const int* __restrict__ cntcl,
    unsigned short* __restrict__ Hout, float* __restrict__ out,
    int Kd, int Nd, int RT, int NT, int capR) {
  __shared__ __align__(16) char smem[98304];  // 3 x 32KB

  // ---- bijective XCD swizzle (m204): contiguous logical ids per XCD ----
  int nwg = gridDim.x;
  int qq = nwg >> 3, rr = nwg & 7;
  int xcd = blockIdx.x & 7, idx = blockIdx.x >> 3;
  int bid = (xcd < rr ? xcd * (qq + 1) : rr * (qq + 1) + (xcd - rr) * qq) + idx;

  int e = bid / (RT * NT);
  int rt = (bid / NT) % RT;
  int nt = bid % NT;
  int cnt = cntcl[e];
  int r0 = rt * 256;
  if (r0 >= cnt) return;  // block-uniform early exit
  int n0 = nt * 256;

  int tid = threadIdx.x;
  int lane = tid & 63;
  int wid = tid >> 6;      // 0..7
  int wr = wid >> 2;       // 0..1  (M half)
  int wc = wid & 3;        // 0..3  (N quarter)
  int l16 = lane & 15, q = lane >> 4;

  // ---- staging source pointers: 2 rounds of 128 rows, 16B per thread ----
  int srow = wid * 16 + (lane >> 2);             // row within a 128-row round
  int cg = (lane & 3) ^ ((lane >> 3) & 3);       // pre-swizzled source chunk
  const char* pA[2];
  const char* pB[2];
#pragma unroll
  for (int rnd = 0; rnd < 2; ++rnd) {
    int r = rnd * 128 + srow;                    // tile-local row 0..255
    const unsigned short* arow;
    if (MODE == 0) {
      int tok = list[e * capR + r0 + r];
      arow = A + (size_t)tok * Kd;
    } else {
      arow = A + (size_t)(e * capR + r0 + r) * Kd;
    }
    pA[rnd] = (const char*)arow + cg * 16;
    pB[rnd] = (const char*)(Bt + (size_t)e * Nd * Kd + (size_t)(n0 + r) * Kd) +
              cg * 16;
  }
  unsigned stbase = wid * 1024;  // wave-uniform LDS staging base (+lane*16 HW)

#define STAGE(tt, bufi)                                   \
  do {                                                    \
    char* dst_ = smem + (bufi) * 32768 + stbase;          \
    int off_ = (tt) * 64;                                 \
    gload_lds16(pA[0] + off_, dst_);                      \
    gload_lds16(pA[1] + off_, dst_ + 8192);               \
    gload_lds16(pB[0] + off_, dst_ + 16384);              \
    gload_lds16(pB[1] + off_, dst_ + 16384 + 8192);       \
  } while (0)

  floatx4 acc[8][4];
#pragma unroll
  for (int i = 0; i < 8; ++i)
#pragma unroll
    for (int j = 0; j < 4; ++j) acc[i][j] = 0.0f;

  // ---- read-side swizzle: chunk q ^ ((row>>1)&3); row bits1..2==lane bits1..2
  int sw = ((q ^ ((lane >> 1) & 3)) << 4);
  int arl = wr * 128 + l16;  // A row base within 256-row tile
  int brl = wc * 64 + l16;   // B row base within 256-row tile

  int nk = Kd / 32;

  // ---- prologue: stage tiles 0 and 1 ----
  STAGE(0, 0);
  STAGE(1, 1);
  VM_WAIT4;  // tile 0 complete (own 4 oldest)
  __builtin_amdgcn_s_barrier();

  int cur = 0;
  for (int t = 0; t < nk; ++t) {
    const char* Ab = smem + cur * 32768;
    const char* Bb = Ab + 16384;
    bool pre = (t + 2) < nk;
    int nx2 = cur + 2; if (nx2 >= 3) nx2 -= 3;

    // ---------------- phase 1: rows i=0..3 ----------------
    bf16x8 af[4], bfr[4];
#pragma unroll
    for (int i = 0; i < 4; ++i)
      af[i] = *(const bf16x8*)(Ab + (arl + i * 16) * 64 + sw);
#pragma unroll
    for (int j = 0; j < 4; ++j)
      bfr[j] = *(const bf16x8*)(Bb + (brl + j * 16) * 64 + sw);
    if (pre) STAGE(t + 2, nx2);
    __builtin_amdgcn_s_barrier();
    __builtin_amdgcn_s_setprio(1);
#pragma unroll
    for (int i = 0; i < 4; ++i)
#pragma unroll
      for (int j = 0; j < 4; ++j)
        acc[i][j] = __builtin_amdgcn_mfma_f32_16x16x32_bf16(af[i], bfr[j],
                                                            acc[i][j], 0, 0, 0);
    __builtin_amdgcn_s_setprio(0);
    __builtin_amdgcn_s_barrier();

    // ---------------- phase 2: rows i=4..7 ----------------
    bf16x8 ag[4];
#pragma unroll
    for (int i = 0; i < 4; ++i)
      ag[i] = *(const bf16x8*)(Ab + (arl + 64 + i * 16) * 64 + sw);
    __builtin_amdgcn_s_barrier();
    __builtin_amdgcn_s_setprio(1);
#pragma unroll
    for (int i = 0; i < 4; ++i)
#pragma unroll
      for (int j = 0; j < 4; ++j)
        acc[4 + i][j] = __builtin_amdgcn_mfma_f32_16x16x32_bf16(
            ag[i], bfr[j], acc[4 + i][j], 0, 0, 0);
    __builtin_amdgcn_s_setprio(0);
    if (pre) { VM_WAIT4; } else { VM_WAIT0; }  // publish tile t+1
    __builtin_amdgcn_s_barrier();
    cur = (cur + 1 == 3) ? 0 : cur + 1;
  }
#undef STAGE

  // ------------------------------- epilogue ---------------------------------
  float bv[4];
#pragma unroll
  for (int j = 0; j < 4; ++j)
    bv[j] = bias[(size_t)e * Nd + n0 + wc * 64 + j * 16 + l16];

  if (MODE == 0) {
#pragma unroll
    for (int i = 0; i < 8; ++i) {
      int rowb = r0 + wr * 128 + i * 16 + q * 4;
#pragma unroll
      for (int j = 0; j < 4; ++j) {
        int col = n0 + wc * 64 + j * 16 + l16;
#pragma unroll
        for (int r = 0; r < 4; ++r) {
          float v = acc[i][j][r] + bv[j];
          v = v > 0.0f ? v : 0.0f;
          Hout[(size_t)(e * capR + rowb + r) * Nd + col] = f2bf(v);
        }
      }
    }
  } else {
#pragma unroll
    for (int i = 0; i < 8; ++i) {
      int rowb = r0 + wr * 128 + i * 16 + q * 4;
      int tok[4]; float wv[4];
#pragma unroll
      for (int r = 0; r < 4; ++r) {
        tok[r] = list[e * capR + rowb + r];
        wv[r] = wlist[e * capR + rowb + r];
      }
#pragma unroll
      for (int j = 0; j < 4; ++j) {
        int col = n0 + wc * 64 + j * 16 + l16;
#pragma unroll
        for (int r = 0; r < 4; ++r) {
          float v = (acc[i][j][r] + bv[j]) * wv[r];
          atomicAdd(&out[(size_t)tok[r] * Nd + col], v);
        }
      }
    }
  }
}

// ------------------------------------ host ----------------------------------
extern "C" void kernel_launch(void* const* d_in, const int* in_sizes, int n_in,
                              void* d_out, int out_size, void* d_ws,
                              size_t ws_size, hipStream_t stream) {
  const float* feat  = (const float*)d_in[0];
  const float* Wg    = (const float*)d_in[1];
  const float* bg    = (const float*)d_in[2];
  const float* W1    = (const float*)d_in[3];
  const float* b1    = (const float*)d_in[4];
  const float* W2    = (const float*)d_in[5];
  const float* b2    = (const float*)d_in[6];
  const float* ebias = (const float*)d_in[7];

  const int E = 16;
  const int B = 16384, F = 1024, Hd = 4096, O = 1024;
  const int cap = 2560;            // ceil(1.25*B*2/E)
  const int capR = 2560;           // multiple of 256
  const int nchunk = B / 256;      // 64
  const int RT = capR / 256;       // 10

  char* p = (char*)d_ws;
  auto carve = [&](size_t bytes) {
    char* r = p;
    p += (bytes + 255) & ~(size_t)255;
    return r;
  };
  unsigned short* featbf = (unsigned short*)carve((size_t)B * F * 2);
  unsigned short* W1T = (unsigned short*)carve((size_t)E * Hd * F * 2);
  unsigned short* W2T = (unsigned short*)carve((size_t)E * O * Hd * 2);
  unsigned short* Hbuf = (unsigned short*)carve((size_t)E * capR * Hd * 2);
  int* topki = (int*)carve((size_t)B * 2 * 4);
  float* topkw = (float*)carve((size_t)B * 2 * 4);
  int* hist = (int*)carve((size_t)nchunk * 16 * 4);
  int* choff = (int*)carve((size_t)nchunk * 16 * 4);
  int* cntcl = (int*)carve(16 * 4);
  int* list = (int*)carve((size_t)E * capR * 4);
  float* wlist = (float*)carve((size_t)E * capR * 4);

  hipMemsetAsync(d_out, 0, (size_t)B * O * sizeof(float), stream);
  hipMemsetAsync(hist, 0, (size_t)nchunk * 16 * 4, stream);

  k_cvt_bf16<<<(B * F / 4 + 255) / 256, 256, 0, stream>>>(feat, featbf,
                                                          (long)B * F / 4);
  dim3 tb(32, 8);
  k_txp_bf16<<<dim3(Hd / 32, F / 32, E), tb, 0, stream>>>(W1, W1T, F, Hd);
  k_txp_bf16<<<dim3(O / 32, Hd / 32, E), tb, 0, stream>>>(W2, W2T, Hd, O);
  k_gating<<<256, 256, 0, stream>>>(feat, Wg, bg, ebias, topki, topkw, hist, B, F);
  k_scan<<<1, 64, 0, stream>>>(hist, choff, cntcl, nchunk, cap);
  k_build<<<nchunk, 64, 0, stream>>>(topki, topkw, choff, list, wlist, cap, capR);
  k_padfill<<<E, 256, 0, stream>>>(cntcl, list, wlist, capR);

  k_gemm<0><<<E * RT * (Hd / 256), 512, 0, stream>>>(
      featbf, W1T, b1, list, wlist, cntcl, Hbuf, nullptr, F, Hd, RT, Hd / 256,
      capR);
  k_gemm<1><<<E * RT * (O / 256), 512, 0, stream>>>(
      Hbuf, W2T, b2, list, wlist, cntcl, nullptr, (float*)d_out, Hd, O, RT,
      O / 256, capR);
}

// Round 3
// 1537.398 us; speedup vs baseline: 1.1448x; 1.1448x over previous
//
#include <hip/hip_runtime.h>
#include <math.h>

// ---------------------------------------------------------------------------
// Aux-free MoE, capacity-routed top-2, E=16 experts.
// B=16384, F=1024, H=4096, O=1024, cap=2560.
// GEMMs: m97-lineage 128x128 tile, BK=32, double-buffered LDS (32KB),
// T3-minimum schedule, 3 blocks/CU TLP, XOR chunk swizzle, XCD swizzle.
// MODE1 stores per-slot outputs (no atomics); k_combine gathers per token.
// Gating in fp64 to match the reference's expert selection exactly.
// ---------------------------------------------------------------------------

typedef __attribute__((ext_vector_type(8))) short bf16x8;
typedef __attribute__((ext_vector_type(4))) float floatx4;

static __device__ __forceinline__ unsigned short f2bf(float f) {
  union { float f; unsigned u; } v; v.f = f;
  unsigned u = v.u;
  return (unsigned short)((u + 0x7fffu + ((u >> 16) & 1u)) >> 16);  // RNE
}

static __device__ __forceinline__ void gload_lds16(const void* g, void* l) {
  __builtin_amdgcn_global_load_lds(
      (const __attribute__((address_space(1))) unsigned int*)g,
      (__attribute__((address_space(3))) unsigned int*)l, 16, 0, 0);
}

// --------------------------- fp32 -> bf16 convert ---------------------------
__global__ void k_cvt_bf16(const float* __restrict__ src,
                           unsigned short* __restrict__ dst, long n4) {
  long i = (long)blockIdx.x * blockDim.x + threadIdx.x;
  if (i >= n4) return;
  float4 f = ((const float4*)src)[i];
  ushort4 o;
  o.x = f2bf(f.x); o.y = f2bf(f.y); o.z = f2bf(f.z); o.w = f2bf(f.w);
  ((ushort4*)dst)[i] = o;
}

// ----------------- transpose + convert: (E,K,N) f32 -> (E,N,K) bf16 --------
__global__ void k_txp_bf16(const float* __restrict__ src,
                           unsigned short* __restrict__ dst, int Kd, int Nd) {
  __shared__ float tile[32][33];
  int e = blockIdx.z;
  int n0 = blockIdx.x * 32;
  int k0 = blockIdx.y * 32;
  int tx = threadIdx.x;  // 0..31
  int ty = threadIdx.y;  // 0..7
  const float* s = src + (size_t)e * Kd * Nd;
#pragma unroll
  for (int j = 0; j < 4; ++j) {
    int k = ty + j * 8;
    tile[k][tx] = s[(size_t)(k0 + k) * Nd + n0 + tx];
  }
  __syncthreads();
  unsigned short* d = dst + (size_t)e * Kd * Nd;
#pragma unroll
  for (int j = 0; j < 4; ++j) {
    int n = ty + j * 8;
    d[(size_t)(n0 + n) * Kd + k0 + tx] = f2bf(tile[tx][n]);
  }
}

// ------------------------------- gating (fp64) ------------------------------
__global__ __launch_bounds__(256) void k_gating(
    const float* __restrict__ feat, const float* __restrict__ Wg,
    const float* __restrict__ bg, const float* __restrict__ ebias,
    int* __restrict__ topki, float* __restrict__ topkw,
    int* __restrict__ hist, int B, int F) {
  __shared__ float WgS[16 * 1024];  // 64 KB
  for (int i = threadIdx.x; i < 16 * F; i += blockDim.x) WgS[i] = Wg[i];
  __syncthreads();
  int lane = threadIdx.x & 63;
  int wid = threadIdx.x >> 6;
  int gw = blockIdx.x * 4 + wid;
  int nw = gridDim.x * 4;
  int per = B / nw;
  for (int it = 0; it < per; ++it) {
    int t = gw * per + it;
    double acc[16];
#pragma unroll
    for (int e = 0; e < 16; ++e) acc[e] = 0.0;
    const float* fr = feat + (size_t)t * F;
    for (int c = 0; c < F / 64; ++c) {
      double fd = (double)fr[c * 64 + lane];
#pragma unroll
      for (int e = 0; e < 16; ++e)
        acc[e] += fd * (double)WgS[e * F + c * 64 + lane];
    }
#pragma unroll
    for (int e = 0; e < 16; ++e) {
#pragma unroll
      for (int off = 32; off >= 1; off >>= 1)
        acc[e] += __shfl_xor(acc[e], off);
    }
    double s[16];
#pragma unroll
    for (int e = 0; e < 16; ++e)
      s[e] = acc[e] + (double)bg[e] + (double)ebias[e];
    int e1 = 0; double s1 = s[0];
#pragma unroll
    for (int e = 1; e < 16; ++e) if (s[e] > s1) { s1 = s[e]; e1 = e; }
    int e2 = -1; double s2 = -1e300;
#pragma unroll
    for (int e = 0; e < 16; ++e)
      if (e != e1 && s[e] > s2) { s2 = s[e]; e2 = e; }
    double d = exp(s2 - s1);
    float w1 = (float)(1.0 / (1.0 + d));
    float w2 = (float)(d / (1.0 + d));
    if (lane == 0) {
      topki[t * 2 + 0] = e1; topki[t * 2 + 1] = e2;
      topkw[t * 2 + 0] = w1; topkw[t * 2 + 1] = w2;
      atomicAdd(&hist[(t >> 8) * 16 + e1], 1);
      atomicAdd(&hist[(t >> 8) * 16 + e2], 1);
    }
  }
}

// ------------------------- chunk-offset scan (1 block) ----------------------
__global__ void k_scan(const int* __restrict__ hist, int* __restrict__ choff,
                       int* __restrict__ cntcl, int nchunk, int cap) {
  int e = threadIdx.x;
  if (e < 16) {
    int off = 0;
    for (int c = 0; c < nchunk; ++c) {
      choff[c * 16 + e] = off;
      off += hist[c * 16 + e];
    }
    cntcl[e] = off < cap ? off : cap;
  }
}

// ------------- build per-expert slot lists + per-token slot ids -------------
__global__ __launch_bounds__(64) void k_build(
    const int* __restrict__ topki, const int* __restrict__ choff,
    int* __restrict__ list, int* __restrict__ slots, int cap, int capR) {
  int c = blockIdx.x;
  int lane = threadIdx.x;
  int run[16];
#pragma unroll
  for (int e = 0; e < 16; ++e) run[e] = choff[c * 16 + e];
  unsigned long long below = (lane == 63) ? 0x7fffffffffffffffull
                                          : ((1ull << lane) - 1ull);
  for (int r = 0; r < 4; ++r) {
    int t = c * 256 + r * 64 + lane;
    int e1 = topki[t * 2 + 0], e2 = topki[t * 2 + 1];
    int p1 = -1, p2 = -1;
#pragma unroll
    for (int e = 0; e < 16; ++e) {
      unsigned long long m = __ballot(e1 == e) | __ballot(e2 == e);
      int rk = run[e] + __popcll(m & below);
      if (e1 == e) p1 = rk;
      if (e2 == e) p2 = rk;
      run[e] += __popcll(m);
    }
    if (p1 < cap) list[e1 * capR + p1] = t;
    if (p2 < cap) list[e2 * capR + p2] = t;
    slots[t * 2 + 0] = (p1 < cap) ? p1 : -1;
    slots[t * 2 + 1] = (p2 < cap) ? p2 : -1;
  }
}

// --------------------------- pad unused slots (token 0) ---------------------
__global__ void k_padfill(const int* __restrict__ cntcl, int* __restrict__ list,
                          int capR) {
  int e = blockIdx.x;
  int cnt = cntcl[e];
  for (int s = cnt + (int)threadIdx.x; s < capR; s += (int)blockDim.x)
    list[e * capR + s] = 0;
}

// ------------------------------ bf16 MFMA GEMM ------------------------------
// 128x128 tile, BK=32, 4 waves (2x2, 64x64 out each), double-buffered 2x16KB.
// Row = 4 x 16B chunks stored at slot = chunk ^ ((row>>1)&3) via pre-swizzled
// global source (linear global_load_lds dest); reads apply the same XOR.
// Per K-step: STAGE(t+1 -> other buf); ds_read 8x b128; setprio(1) 16 MFMA
// setprio(0); s_waitcnt vmcnt(0); s_barrier.  3 blocks/CU provide the TLP
// that hides the drain (m97-measured 874 TF structure).
// MODE 0: A rows gathered from featbf via list; epilogue relu(acc+b1) -> Hout
// MODE 1: A rows from Hbuf; epilogue (acc+b2) -> Ybuf f32 (no weight, no atomics)
#define VM_WAIT0 asm volatile("s_waitcnt vmcnt(0)" ::: "memory")

template <int MODE>
__global__ __launch_bounds__(256, 3) void k_gemm(
    const unsigned short* __restrict__ A, const unsigned short* __restrict__ Bt,
    const float* __restrict__ bias, const int* __restrict__ list,
    const int* __restrict__ cntcl, unsigned short* __restrict__ Hout,
    float* __restrict__ Yout, int Kd, int Nd, int RT, int NT, int capR) {
  __shared__ __align__(16) char smem[32768];  // 2 x 16KB

  // ---- bijective XCD swizzle (m204): contiguous logical ids per XCD ----
  int nwg = gridDim.x;
  int qq = nwg >> 3, rr = nwg & 7;
  int xcd = blockIdx.x & 7, idx = blockIdx.x >> 3;
  int bid = (xcd < rr ? xcd * (qq + 1) : rr * (qq + 1) + (xcd - rr) * qq) + idx;

  int e = bid / (RT * NT);
  int rt = (bid / NT) % RT;
  int nt = bid % NT;
  int cnt = cntcl[e];
  int r0 = rt * 128;
  if (r0 >= cnt) return;  // block-uniform early exit
  int n0 = nt * 128;

  int tid = threadIdx.x;
  int lane = tid & 63;
  int wid = tid >> 6;      // 0..3
  int wr = wid >> 1;       // 0..1
  int wc = wid & 1;        // 0..1
  int l16 = lane & 15, q = lane >> 4;

  // ---- staging source pointers (rows srow, srow+64), pre-swizzled chunk ----
  int srow = tid >> 2;                         // 0..63
  int cg = (tid & 3) ^ ((srow >> 1) & 3);      // source chunk for this slot
  const char* pA0;
  const char* pA1;
  if (MODE == 0) {
    int tok0 = list[e * capR + r0 + srow];
    int tok1 = list[e * capR + r0 + srow + 64];
    pA0 = (const char*)(A + (size_t)tok0 * Kd) + cg * 16;
    pA1 = (const char*)(A + (size_t)tok1 * Kd) + cg * 16;
  } else {
    pA0 = (const char*)(A + (size_t)(e * capR + r0 + srow) * Kd) + cg * 16;
    pA1 = pA0 + (size_t)64 * Kd * 2;
  }
  const char* pB0 =
      (const char*)(Bt + (size_t)e * Nd * Kd + (size_t)(n0 + srow) * Kd) +
      cg * 16;
  const char* pB1 = pB0 + (size_t)64 * Kd * 2;
  unsigned stbase = wid * 1024;  // wave-uniform LDS base (+lane*16 by HW)

#define STAGE(tt, bufi)                                  \
  do {                                                   \
    char* dst_ = smem + (bufi) * 16384 + stbase;         \
    int off_ = (tt) * 64;                                \
    gload_lds16(pA0 + off_, dst_);                       \
    gload_lds16(pA1 + off_, dst_ + 4096);                \
    gload_lds16(pB0 + off_, dst_ + 8192);                \
    gload_lds16(pB1 + off_, dst_ + 12288);               \
  } while (0)

  floatx4 acc[4][4];
#pragma unroll
  for (int i = 0; i < 4; ++i)
#pragma unroll
    for (int j = 0; j < 4; ++j) acc[i][j] = 0.0f;

  // ---- read-side swizzle: chunk q ^ ((row>>1)&3) ----
  int sw = ((q ^ ((l16 >> 1) & 3)) << 4);
  int arl = wr * 64 + l16;
  int brl = wc * 64 + l16;

  int nk = Kd / 32;

  STAGE(0, 0);
  VM_WAIT0;
  __builtin_amdgcn_s_barrier();

  int cur = 0;
  for (int t = 0; t < nk; ++t) {
    const char* Ab = smem + cur * 16384;
    const char* Bb = Ab + 8192;
    if (t + 1 < nk) STAGE(t + 1, cur ^ 1);
    bf16x8 af[4], bfr[4];
#pragma unroll
    for (int i = 0; i < 4; ++i)
      af[i] = *(const bf16x8*)(Ab + (arl + i * 16) * 64 + sw);
#pragma unroll
    for (int j = 0; j < 4; ++j)
      bfr[j] = *(const bf16x8*)(Bb + (brl + j * 16) * 64 + sw);
    __builtin_amdgcn_s_setprio(1);
#pragma unroll
    for (int i = 0; i < 4; ++i)
#pragma unroll
      for (int j = 0; j < 4; ++j)
        acc[i][j] = __builtin_amdgcn_mfma_f32_16x16x32_bf16(af[i], bfr[j],
                                                            acc[i][j], 0, 0, 0);
    __builtin_amdgcn_s_setprio(0);
    VM_WAIT0;                        // next tile's LDS writes landed (per-wave)
    __builtin_amdgcn_s_barrier();    // all waves done reading cur & staged
    cur ^= 1;
  }
#undef STAGE

  // ------------------------------- epilogue ---------------------------------
  float bv[4];
#pragma unroll
  for (int j = 0; j < 4; ++j)
    bv[j] = bias[(size_t)e * Nd + n0 + wc * 64 + j * 16 + l16];

  if (MODE == 0) {
#pragma unroll
    for (int i = 0; i < 4; ++i) {
      int rowb = r0 + wr * 64 + i * 16 + q * 4;
#pragma unroll
      for (int j = 0; j < 4; ++j) {
        int col = n0 + wc * 64 + j * 16 + l16;
#pragma unroll
        for (int r = 0; r < 4; ++r) {
          float v = acc[i][j][r] + bv[j];
          v = v > 0.0f ? v : 0.0f;
          Hout[(size_t)(e * capR + rowb + r) * Nd + col] = f2bf(v);
        }
      }
    }
  } else {
#pragma unroll
    for (int i = 0; i < 4; ++i) {
      int rowb = r0 + wr * 64 + i * 16 + q * 4;
#pragma unroll
      for (int j = 0; j < 4; ++j) {
        int col = n0 + wc * 64 + j * 16 + l16;
#pragma unroll
        for (int r = 0; r < 4; ++r)
          Yout[(size_t)(e * capR + rowb + r) * Nd + col] = acc[i][j][r] + bv[j];
      }
    }
  }
}

// --------------- combine: out[t] = w1*Y[e1,s1] + w2*Y[e2,s2] ----------------
__global__ __launch_bounds__(256) void k_combine(
    const float* __restrict__ Y, const int* __restrict__ topki,
    const float* __restrict__ topkw, const int* __restrict__ slots,
    float* __restrict__ out, int capR, int O) {
  int t = blockIdx.x;
  int c = threadIdx.x;  // float4 index, 256 x 4 = 1024 cols
  int e1 = topki[t * 2 + 0], e2 = topki[t * 2 + 1];
  int s1 = slots[t * 2 + 0], s2 = slots[t * 2 + 1];
  float w1 = topkw[t * 2 + 0], w2 = topkw[t * 2 + 1];
  float4 r = make_float4(0.f, 0.f, 0.f, 0.f);
  if (s1 >= 0) {
    float4 a = ((const float4*)(Y + (size_t)(e1 * capR + s1) * O))[c];
    r.x += w1 * a.x; r.y += w1 * a.y; r.z += w1 * a.z; r.w += w1 * a.w;
  }
  if (s2 >= 0) {
    float4 b = ((const float4*)(Y + (size_t)(e2 * capR + s2) * O))[c];
    r.x += w2 * b.x; r.y += w2 * b.y; r.z += w2 * b.z; r.w += w2 * b.w;
  }
  ((float4*)(out + (size_t)t * O))[c] = r;
}

// ------------------------------------ host ----------------------------------
extern "C" void kernel_launch(void* const* d_in, const int* in_sizes, int n_in,
                              void* d_out, int out_size, void* d_ws,
                              size_t ws_size, hipStream_t stream) {
  const float* feat  = (const float*)d_in[0];
  const float* Wg    = (const float*)d_in[1];
  const float* bg    = (const float*)d_in[2];
  const float* W1    = (const float*)d_in[3];
  const float* b1    = (const float*)d_in[4];
  const float* W2    = (const float*)d_in[5];
  const float* b2    = (const float*)d_in[6];
  const float* ebias = (const float*)d_in[7];

  const int E = 16;
  const int B = 16384, F = 1024, Hd = 4096, O = 1024;
  const int cap = 2560;            // ceil(1.25*B*2/E)
  const int capR = 2560;           // multiple of 128
  const int nchunk = B / 256;      // 64
  const int RT = capR / 128;       // 20

  char* p = (char*)d_ws;
  auto carve = [&](size_t bytes) {
    char* r = p;
    p += (bytes + 255) & ~(size_t)255;
    return r;
  };
  unsigned short* featbf = (unsigned short*)carve((size_t)B * F * 2);
  unsigned short* W1T = (unsigned short*)carve((size_t)E * Hd * F * 2);
  unsigned short* W2T = (unsigned short*)carve((size_t)E * O * Hd * 2);
  unsigned short* Hbuf = (unsigned short*)carve((size_t)E * capR * Hd * 2);
  int* topki = (int*)carve((size_t)B * 2 * 4);
  float* topkw = (float*)carve((size_t)B * 2 * 4);
  int* hist = (int*)carve((size_t)nchunk * 16 * 4);
  int* choff = (int*)carve((size_t)nchunk * 16 * 4);
  int* cntcl = (int*)carve(16 * 4);
  int* list = (int*)carve((size_t)E * capR * 4);
  int* slots = (int*)carve((size_t)B * 2 * 4);
  // Ybuf (E*capR*O f32 = 160 MB) aliases featbf+W1T (dead after k_gemm<0>);
  // the sizes match exactly: B*F*2 + E*Hd*F*2 == E*capR*O*4.
  float* Ybuf = (float*)featbf;

  hipMemsetAsync(hist, 0, (size_t)nchunk * 16 * 4, stream);

  k_cvt_bf16<<<(B * F / 4 + 255) / 256, 256, 0, stream>>>(feat, featbf,
                                                          (long)B * F / 4);
  dim3 tb(32, 8);
  k_txp_bf16<<<dim3(Hd / 32, F / 32, E), tb, 0, stream>>>(W1, W1T, F, Hd);
  k_txp_bf16<<<dim3(O / 32, Hd / 32, E), tb, 0, stream>>>(W2, W2T, Hd, O);
  k_gating<<<256, 256, 0, stream>>>(feat, Wg, bg, ebias, topki, topkw, hist, B, F);
  k_scan<<<1, 64, 0, stream>>>(hist, choff, cntcl, nchunk, cap);
  k_build<<<nchunk, 64, 0, stream>>>(topki, choff, list, slots, cap, capR);
  k_padfill<<<E, 256, 0, stream>>>(cntcl, list, capR);

  k_gemm<0><<<E * RT * (Hd / 128), 256, 0, stream>>>(
      featbf, W1T, b1, list, cntcl, Hbuf, nullptr, F, Hd, RT, Hd / 128, capR);
  k_gemm<1><<<E * RT * (O / 128), 256, 0, stream>>>(
      Hbuf, W2T, b2, list, cntcl, nullptr, Ybuf, Hd, O, RT, O / 128, capR);
  k_combine<<<B, 256, 0, stream>>>(Ybuf, topki, topkw, slots, (float*)d_out,
                                   capR, O);
}